// Round 4
// baseline (167.427 us; speedup 1.0000x reference)
//
#include <hip/hip_runtime.h>

#define HW (384 * 384)      // 147456 per sample
#define BATCH 32
#define HW4 (HW / 4)        // 36864 float4 per sample
#define ITER 2              // float4 chunks per thread in k1/k3
#define BLOCKS_PER_SAMPLE 72    // 72 * 256 threads * 4 elems * ITER = 147456
// R4 geometry: 2304 blocks = 9216 waves -> fills all 8192 wave slots (R3's
// 1152-block grid capped occupancy at 56%). ITER=2 with all 14 float4 loads
// issued before arithmetic -> 14 loads in flight per wave (~70 VGPR).

// stats layout in d_ws (4-byte slots):
//   [0..31]    fg_num  (float)
//   [32..63]   bg_num  (float)
//   [64..95]   num_fast (float)  = sum l_total*(fg+bg) per sample
//   [96..127]  den_fast (float)  = sum conf*(fg+bg) per sample
//   [128..159] thresh  (float)   (general path only)
//   [160..191] flag    (uint)    1 = fast path (hard == bg)
//   [192]      gnum    (float)
//   [193]      gden    (float)
#define S_FG 0
#define S_BG 32
#define S_NUMF 64
#define S_DENF 96
#define S_THR 128
#define S_FLAG 160
#define S_GNUM 192
#define S_GDEN 193

// Native device-scope fp32 atomic add (global_atomic_add_f32), avoiding the
// CAS retry loop hipcc emits for plain atomicAdd(float*) without
// -munsafe-fp-atomics (R0->R1: 233us -> 66us).
__device__ __forceinline__ void fadd_agent(float* p, float v) {
    __hip_atomic_fetch_add(p, v, __ATOMIC_RELAXED, __HIP_MEMORY_SCOPE_AGENT);
}

__device__ __forceinline__ void wave_reduce4(float& a, float& b, float& c, float& d) {
#pragma unroll
    for (int off = 32; off; off >>= 1) {
        a += __shfl_xor(a, off);
        b += __shfl_xor(b, off);
        c += __shfl_xor(c, off);
        d += __shfl_xor(d, off);
    }
}

// K1: one pass over all 7 arrays. Per-sample fg_num, bg_num, and speculative
// fast-path sums (train_mask = fg + bg).
__global__ __launch_bounds__(256) void k1_stats(
        const float4* __restrict__ rt, const float4* __restrict__ at,
        const float4* __restrict__ rp, const float4* __restrict__ ap,
        const float4* __restrict__ cf, const float4* __restrict__ fg,
        const float4* __restrict__ bg, float* __restrict__ stats) {
    const int b = blockIdx.y;
    const int base = b * HW4 + blockIdx.x * (256 * ITER) + threadIdx.x;
    // Issue ALL loads before any arithmetic: 14 independent loads in flight.
    float4 vrt[ITER], vat[ITER], vrp[ITER], vap[ITER], vcf[ITER], vfg[ITER], vbg[ITER];
#pragma unroll
    for (int it = 0; it < ITER; ++it) {
        const int idx = base + it * 256;
        vrt[it] = rt[idx]; vat[it] = at[idx]; vrp[it] = rp[idx]; vap[it] = ap[idx];
        vcf[it] = cf[idx]; vfg[it] = fg[idx]; vbg[it] = bg[idx];
    }
    float sfg = 0.f, sbg = 0.f, snum = 0.f, sden = 0.f;
#pragma unroll
    for (int it = 0; it < ITER; ++it) {
#pragma unroll
        for (int j = 0; j < 4; ++j) {
            float r = (&vrt[it].x)[j] - (&vrp[it].x)[j];
            float a = (&vat[it].x)[j] - (&vap[it].x)[j];
            float c = (&vcf[it].x)[j];
            float lt = (r * r + a * a) * c;
            float f = (&vfg[it].x)[j], g = (&vbg[it].x)[j];
            float train = f + g;
            sfg += f;
            sbg += g;
            snum += lt * train;
            sden += c * train;
        }
    }
    wave_reduce4(sfg, sbg, snum, sden);
    __shared__ float sh[4][4];
    const int wave = threadIdx.x >> 6;
    if ((threadIdx.x & 63) == 0) {
        sh[wave][0] = sfg; sh[wave][1] = sbg; sh[wave][2] = snum; sh[wave][3] = sden;
    }
    __syncthreads();
    if (threadIdx.x < 4) {
        const int q = threadIdx.x;
        float s = sh[0][q] + sh[1][q] + sh[2][q] + sh[3][q];
        fadd_agent(&stats[q * 32 + b], s);   // q*32: S_FG/S_BG/S_NUMF/S_DENF
    }
}

// K2: one block per sample. Decide fast path (neg_num == bg_num -> hard == bg,
// proven exact) or run 4-pass radix-256 select for the exact k-th largest
// neg_loss value (uint bit pattern order == float order for non-negative).
__global__ __launch_bounds__(512) void k2_select(
        const float* __restrict__ rt, const float* __restrict__ at,
        const float* __restrict__ rp, const float* __restrict__ ap,
        const float* __restrict__ cf, const float* __restrict__ bg,
        float* __restrict__ stats) {
    const int b = blockIdx.x;
    const float fg_num = stats[S_FG + b];
    const float bg_num = stats[S_BG + b];
    int neg = (int)(fg_num * 3.0f);
    if (neg < 10000) neg = 10000;
    const int bgn = (int)bg_num;
    unsigned* flags = (unsigned*)stats;
    if (neg >= bgn) {
        // neg_num == bg_num: thresh is min bg loss (or 0) -> hard == bg exactly.
        if (threadIdx.x == 0) {
            flags[S_FLAG + b] = 1u;
            fadd_agent(&stats[S_GNUM], stats[S_NUMF + b]);
            fadd_agent(&stats[S_GDEN], stats[S_DENF + b]);
        }
        return;
    }
    if (threadIdx.x == 0) flags[S_FLAG + b] = 0u;

    __shared__ unsigned hist[256];
    __shared__ unsigned sh_prefix, sh_k;
    unsigned prefix = 0;
    unsigned k = (unsigned)neg;  // k >= 10000 >= 1 here
    const long base = (long)b * HW;
#pragma unroll 1
    for (int p = 3; p >= 0; --p) {
        for (int i = threadIdx.x; i < 256; i += blockDim.x) hist[i] = 0u;
        __syncthreads();
        const unsigned shift = 8u * (unsigned)p;
        const unsigned himask = (p == 3) ? 0u : (0xFFFFFFFFu << (shift + 8u));
#pragma unroll 1
        for (int i = threadIdx.x; i < HW; i += blockDim.x) {
            long g = base + i;
            float r = rt[g] - rp[g];
            float a = at[g] - ap[g];
            float lt = (r * r + a * a) * cf[g];
            float nl = lt * bg[g];
            unsigned v = __float_as_uint(nl);
            if ((v & himask) == prefix) atomicAdd(&hist[(v >> shift) & 255u], 1u);
        }
        __syncthreads();
        if (threadIdx.x == 0) {
            unsigned cum = 0;
            for (int bin = 255; bin >= 0; --bin) {
                unsigned c = hist[bin];
                if (cum + c >= k) {
                    sh_prefix = prefix | ((unsigned)bin << shift);
                    sh_k = k - cum;  // remaining rank within this bin
                    break;
                }
                cum += c;
            }
        }
        __syncthreads();
        prefix = sh_prefix;
        k = sh_k;
        __syncthreads();  // protect hist before next-pass zeroing
    }
    if (threadIdx.x == 0) stats[S_THR + b] = __uint_as_float(prefix);
}

// K3: masked sums for general-path samples only (early-exit on fast flag).
__global__ __launch_bounds__(256) void k3_general(
        const float4* __restrict__ rt, const float4* __restrict__ at,
        const float4* __restrict__ rp, const float4* __restrict__ ap,
        const float4* __restrict__ cf, const float4* __restrict__ fg,
        const float4* __restrict__ bg, float* __restrict__ stats) {
    const int b = blockIdx.y;
    if (((const unsigned*)stats)[S_FLAG + b] != 0u) return;
    const float thresh = stats[S_THR + b];
    const int base = b * HW4 + blockIdx.x * (256 * ITER) + threadIdx.x;
    float snum = 0.f, sden = 0.f, z0 = 0.f, z1 = 0.f;
#pragma unroll
    for (int it = 0; it < ITER; ++it) {
        const int idx = base + it * 256;
        float4 vrt = rt[idx], vat = at[idx], vrp = rp[idx], vap = ap[idx];
        float4 vcf = cf[idx], vfg = fg[idx], vbg = bg[idx];
#pragma unroll
        for (int j = 0; j < 4; ++j) {
            float r = (&vrt.x)[j] - (&vrp.x)[j];
            float a = (&vat.x)[j] - (&vap.x)[j];
            float c = (&vcf.x)[j];
            float lt = (r * r + a * a) * c;
            float f = (&vfg.x)[j], g = (&vbg.x)[j];
            float nl = lt * g;
            float hard = (g != 0.f && nl >= thresh) ? 1.f : 0.f;
            float train = hard + f;
            snum += lt * train;
            sden += c * train;
        }
    }
    wave_reduce4(snum, sden, z0, z1);
    __shared__ float sh[4][2];
    const int wave = threadIdx.x >> 6;
    if ((threadIdx.x & 63) == 0) { sh[wave][0] = snum; sh[wave][1] = sden; }
    __syncthreads();
    if (threadIdx.x < 2) {
        const int q = threadIdx.x;
        float s = sh[0][q] + sh[1][q] + sh[2][q] + sh[3][q];
        fadd_agent(&stats[S_GNUM + q], s);
    }
}

__global__ void k4_final(const float* __restrict__ stats, float* __restrict__ out) {
    out[0] = stats[S_GNUM] / (stats[S_GDEN] + 1e-7f);
}

extern "C" void kernel_launch(void* const* d_in, const int* in_sizes, int n_in,
                              void* d_out, int out_size, void* d_ws, size_t ws_size,
                              hipStream_t stream) {
    const float* rt = (const float*)d_in[0];
    const float* at = (const float*)d_in[1];
    const float* rp = (const float*)d_in[2];
    const float* ap = (const float*)d_in[3];
    const float* cf = (const float*)d_in[4];
    const float* fg = (const float*)d_in[5];
    const float* bg = (const float*)d_in[6];
    float* stats = (float*)d_ws;
    float* out = (float*)d_out;

    hipMemsetAsync(d_ws, 0, 1024, stream);

    dim3 grid(BLOCKS_PER_SAMPLE, BATCH);
    k1_stats<<<grid, 256, 0, stream>>>((const float4*)rt, (const float4*)at,
                                       (const float4*)rp, (const float4*)ap,
                                       (const float4*)cf, (const float4*)fg,
                                       (const float4*)bg, stats);
    k2_select<<<BATCH, 512, 0, stream>>>(rt, at, rp, ap, cf, bg, stats);
    k3_general<<<grid, 256, 0, stream>>>((const float4*)rt, (const float4*)at,
                                         (const float4*)rp, (const float4*)ap,
                                         (const float4*)cf, (const float4*)fg,
                                         (const float4*)bg, stats);
    k4_final<<<1, 1, 0, stream>>>(stats, out);
}

// Round 5
// 167.402 us; speedup vs baseline: 1.0001x; 1.0001x over previous
//
#include <hip/hip_runtime.h>

#define HW (384 * 384)      // 147456 per sample
#define BATCH 32
#define HW4 (HW / 4)        // 36864 float4 per sample
#define ITER 2              // float4 chunks per thread in k1/k3
#define BLOCKS_PER_SAMPLE 72    // 72 * 256 threads * 4 elems * ITER = 147456
// Geometry: 2304 blocks = 9216 waves -> fills all 8192 wave slots.
// R4->R5: compiler kept VGPR=32 by interleaving load/consume (4-load MLP).
// Force all 14 loads in flight with sched_barrier(0) between loads and math.

// stats layout in d_ws (4-byte slots):
//   [0..31]    fg_num  (float)
//   [32..63]   bg_num  (float)
//   [64..95]   num_fast (float)  = sum l_total*(fg+bg) per sample
//   [96..127]  den_fast (float)  = sum conf*(fg+bg) per sample
//   [128..159] thresh  (float)   (general path only)
//   [160..191] flag    (uint)    1 = fast path (hard == bg)
//   [192]      gnum    (float)
//   [193]      gden    (float)
#define S_FG 0
#define S_BG 32
#define S_NUMF 64
#define S_DENF 96
#define S_THR 128
#define S_FLAG 160
#define S_GNUM 192
#define S_GDEN 193

// Native device-scope fp32 atomic add (global_atomic_add_f32), avoiding the
// CAS retry loop hipcc emits for plain atomicAdd(float*) without
// -munsafe-fp-atomics (R0->R1: 233us -> 66us).
__device__ __forceinline__ void fadd_agent(float* p, float v) {
    __hip_atomic_fetch_add(p, v, __ATOMIC_RELAXED, __HIP_MEMORY_SCOPE_AGENT);
}

__device__ __forceinline__ void wave_reduce4(float& a, float& b, float& c, float& d) {
#pragma unroll
    for (int off = 32; off; off >>= 1) {
        a += __shfl_xor(a, off);
        b += __shfl_xor(b, off);
        c += __shfl_xor(c, off);
        d += __shfl_xor(d, off);
    }
}

// K1: one pass over all 7 arrays. Per-sample fg_num, bg_num, and speculative
// fast-path sums (train_mask = fg + bg). All 14 float4 loads issued before
// any arithmetic, pinned by sched_barrier(0) so the compiler cannot fold
// them back into low-VGPR load->consume batches.
__global__ __launch_bounds__(256) void k1_stats(
        const float4* __restrict__ rt, const float4* __restrict__ at,
        const float4* __restrict__ rp, const float4* __restrict__ ap,
        const float4* __restrict__ cf, const float4* __restrict__ fg,
        const float4* __restrict__ bg, float* __restrict__ stats) {
    const int b = blockIdx.y;
    const int base = b * HW4 + blockIdx.x * (256 * ITER) + threadIdx.x;
    float4 vrt[ITER], vat[ITER], vrp[ITER], vap[ITER], vcf[ITER], vfg[ITER], vbg[ITER];
#pragma unroll
    for (int it = 0; it < ITER; ++it) {
        const int idx = base + it * 256;
        vrt[it] = rt[idx]; vat[it] = at[idx]; vrp[it] = rp[idx]; vap[it] = ap[idx];
        vcf[it] = cf[idx]; vfg[it] = fg[idx]; vbg[it] = bg[idx];
    }
    // Nothing below may be hoisted above this point; all 14 loads in flight.
    __builtin_amdgcn_sched_barrier(0);
    float sfg = 0.f, sbg = 0.f, snum = 0.f, sden = 0.f;
#pragma unroll
    for (int it = 0; it < ITER; ++it) {
#pragma unroll
        for (int j = 0; j < 4; ++j) {
            float r = (&vrt[it].x)[j] - (&vrp[it].x)[j];
            float a = (&vat[it].x)[j] - (&vap[it].x)[j];
            float c = (&vcf[it].x)[j];
            float lt = (r * r + a * a) * c;
            float f = (&vfg[it].x)[j], g = (&vbg[it].x)[j];
            float train = f + g;
            sfg += f;
            sbg += g;
            snum += lt * train;
            sden += c * train;
        }
    }
    wave_reduce4(sfg, sbg, snum, sden);
    __shared__ float sh[4][4];
    const int wave = threadIdx.x >> 6;
    if ((threadIdx.x & 63) == 0) {
        sh[wave][0] = sfg; sh[wave][1] = sbg; sh[wave][2] = snum; sh[wave][3] = sden;
    }
    __syncthreads();
    if (threadIdx.x < 4) {
        const int q = threadIdx.x;
        float s = sh[0][q] + sh[1][q] + sh[2][q] + sh[3][q];
        fadd_agent(&stats[q * 32 + b], s);   // q*32: S_FG/S_BG/S_NUMF/S_DENF
    }
}

// K2: one block per sample. Decide fast path (neg_num == bg_num -> hard == bg,
// proven exact) or run 4-pass radix-256 select for the exact k-th largest
// neg_loss value (uint bit pattern order == float order for non-negative).
__global__ __launch_bounds__(512) void k2_select(
        const float* __restrict__ rt, const float* __restrict__ at,
        const float* __restrict__ rp, const float* __restrict__ ap,
        const float* __restrict__ cf, const float* __restrict__ bg,
        float* __restrict__ stats) {
    const int b = blockIdx.x;
    const float fg_num = stats[S_FG + b];
    const float bg_num = stats[S_BG + b];
    int neg = (int)(fg_num * 3.0f);
    if (neg < 10000) neg = 10000;
    const int bgn = (int)bg_num;
    unsigned* flags = (unsigned*)stats;
    if (neg >= bgn) {
        // neg_num == bg_num: thresh is min bg loss (or 0) -> hard == bg exactly.
        if (threadIdx.x == 0) {
            flags[S_FLAG + b] = 1u;
            fadd_agent(&stats[S_GNUM], stats[S_NUMF + b]);
            fadd_agent(&stats[S_GDEN], stats[S_DENF + b]);
        }
        return;
    }
    if (threadIdx.x == 0) flags[S_FLAG + b] = 0u;

    __shared__ unsigned hist[256];
    __shared__ unsigned sh_prefix, sh_k;
    unsigned prefix = 0;
    unsigned k = (unsigned)neg;  // k >= 10000 >= 1 here
    const long base = (long)b * HW;
#pragma unroll 1
    for (int p = 3; p >= 0; --p) {
        for (int i = threadIdx.x; i < 256; i += blockDim.x) hist[i] = 0u;
        __syncthreads();
        const unsigned shift = 8u * (unsigned)p;
        const unsigned himask = (p == 3) ? 0u : (0xFFFFFFFFu << (shift + 8u));
#pragma unroll 1
        for (int i = threadIdx.x; i < HW; i += blockDim.x) {
            long g = base + i;
            float r = rt[g] - rp[g];
            float a = at[g] - ap[g];
            float lt = (r * r + a * a) * cf[g];
            float nl = lt * bg[g];
            unsigned v = __float_as_uint(nl);
            if ((v & himask) == prefix) atomicAdd(&hist[(v >> shift) & 255u], 1u);
        }
        __syncthreads();
        if (threadIdx.x == 0) {
            unsigned cum = 0;
            for (int bin = 255; bin >= 0; --bin) {
                unsigned c = hist[bin];
                if (cum + c >= k) {
                    sh_prefix = prefix | ((unsigned)bin << shift);
                    sh_k = k - cum;  // remaining rank within this bin
                    break;
                }
                cum += c;
            }
        }
        __syncthreads();
        prefix = sh_prefix;
        k = sh_k;
        __syncthreads();  // protect hist before next-pass zeroing
    }
    if (threadIdx.x == 0) stats[S_THR + b] = __uint_as_float(prefix);
}

// K3: masked sums for general-path samples only (early-exit on fast flag).
__global__ __launch_bounds__(256) void k3_general(
        const float4* __restrict__ rt, const float4* __restrict__ at,
        const float4* __restrict__ rp, const float4* __restrict__ ap,
        const float4* __restrict__ cf, const float4* __restrict__ fg,
        const float4* __restrict__ bg, float* __restrict__ stats) {
    const int b = blockIdx.y;
    if (((const unsigned*)stats)[S_FLAG + b] != 0u) return;
    const float thresh = stats[S_THR + b];
    const int base = b * HW4 + blockIdx.x * (256 * ITER) + threadIdx.x;
    float snum = 0.f, sden = 0.f, z0 = 0.f, z1 = 0.f;
#pragma unroll
    for (int it = 0; it < ITER; ++it) {
        const int idx = base + it * 256;
        float4 vrt = rt[idx], vat = at[idx], vrp = rp[idx], vap = ap[idx];
        float4 vcf = cf[idx], vfg = fg[idx], vbg = bg[idx];
#pragma unroll
        for (int j = 0; j < 4; ++j) {
            float r = (&vrt.x)[j] - (&vrp.x)[j];
            float a = (&vat.x)[j] - (&vap.x)[j];
            float c = (&vcf.x)[j];
            float lt = (r * r + a * a) * c;
            float f = (&vfg.x)[j], g = (&vbg.x)[j];
            float nl = lt * g;
            float hard = (g != 0.f && nl >= thresh) ? 1.f : 0.f;
            float train = hard + f;
            snum += lt * train;
            sden += c * train;
        }
    }
    wave_reduce4(snum, sden, z0, z1);
    __shared__ float sh[4][2];
    const int wave = threadIdx.x >> 6;
    if ((threadIdx.x & 63) == 0) { sh[wave][0] = snum; sh[wave][1] = sden; }
    __syncthreads();
    if (threadIdx.x < 2) {
        const int q = threadIdx.x;
        float s = sh[0][q] + sh[1][q] + sh[2][q] + sh[3][q];
        fadd_agent(&stats[S_GNUM + q], s);
    }
}

__global__ void k4_final(const float* __restrict__ stats, float* __restrict__ out) {
    out[0] = stats[S_GNUM] / (stats[S_GDEN] + 1e-7f);
}

extern "C" void kernel_launch(void* const* d_in, const int* in_sizes, int n_in,
                              void* d_out, int out_size, void* d_ws, size_t ws_size,
                              hipStream_t stream) {
    const float* rt = (const float*)d_in[0];
    const float* at = (const float*)d_in[1];
    const float* rp = (const float*)d_in[2];
    const float* ap = (const float*)d_in[3];
    const float* cf = (const float*)d_in[4];
    const float* fg = (const float*)d_in[5];
    const float* bg = (const float*)d_in[6];
    float* stats = (float*)d_ws;
    float* out = (float*)d_out;

    hipMemsetAsync(d_ws, 0, 1024, stream);

    dim3 grid(BLOCKS_PER_SAMPLE, BATCH);
    k1_stats<<<grid, 256, 0, stream>>>((const float4*)rt, (const float4*)at,
                                       (const float4*)rp, (const float4*)ap,
                                       (const float4*)cf, (const float4*)fg,
                                       (const float4*)bg, stats);
    k2_select<<<BATCH, 512, 0, stream>>>(rt, at, rp, ap, cf, bg, stats);
    k3_general<<<grid, 256, 0, stream>>>((const float4*)rt, (const float4*)at,
                                         (const float4*)rp, (const float4*)ap,
                                         (const float4*)cf, (const float4*)fg,
                                         (const float4*)bg, stats);
    k4_final<<<1, 1, 0, stream>>>(stats, out);
}

// Round 6
// 167.304 us; speedup vs baseline: 1.0007x; 1.0006x over previous
//
#include <hip/hip_runtime.h>

#define HW (384 * 384)      // 147456 per sample
#define BATCH 32
#define HW4 (HW / 4)        // 36864 float4 per sample
// k1 geometry: 48 blocks/sample, each block owns 3 CONSECUTIVE 256-float4
// chunks (48*3*256 = 36864). 1536 blocks = 6 blocks/CU even. Software
// pipeline: compute chunk c while chunk c+1's 7 loads are in flight, pinned
// by asm memory clobbers (sched_barrier was a no-op in R5: IR-level load
// sinking ignores it -> VGPR stayed 32 = loads never in flight).
#define K1_BLOCKS 48
// k3 geometry (unchanged from R4/R5; early-exits on fast path)
#define ITER 2
#define K3_BLOCKS 72

// stats layout in d_ws (4-byte slots):
//   [0..31]    fg_num  (float)
//   [32..63]   bg_num  (float)
//   [64..95]   num_fast (float)  = sum l_total*(fg+bg) per sample
//   [96..127]  den_fast (float)  = sum conf*(fg+bg) per sample
//   [128..159] thresh  (float)   (general path only)
//   [160..191] flag    (uint)    1 = fast path (hard == bg)
//   [192]      gnum    (float)
//   [193]      gden    (float)
#define S_FG 0
#define S_BG 32
#define S_NUMF 64
#define S_DENF 96
#define S_THR 128
#define S_FLAG 160
#define S_GNUM 192
#define S_GDEN 193

// Native device-scope fp32 atomic add (global_atomic_add_f32), avoiding the
// CAS retry loop hipcc emits for plain atomicAdd(float*) without
// -munsafe-fp-atomics (R0->R1: 233us -> 66us).
__device__ __forceinline__ void fadd_agent(float* p, float v) {
    __hip_atomic_fetch_add(p, v, __ATOMIC_RELAXED, __HIP_MEMORY_SCOPE_AGENT);
}

__device__ __forceinline__ void wave_reduce4(float& a, float& b, float& c, float& d) {
#pragma unroll
    for (int off = 32; off; off >>= 1) {
        a += __shfl_xor(a, off);
        b += __shfl_xor(b, off);
        c += __shfl_xor(c, off);
        d += __shfl_xor(d, off);
    }
}

// K1: one pass over all 7 arrays. Per-sample fg_num, bg_num, and speculative
// fast-path sums (train_mask = fg + bg). 3-chunk pipelined, loads pinned.
__global__ __launch_bounds__(256) void k1_stats(
        const float4* __restrict__ rt, const float4* __restrict__ at,
        const float4* __restrict__ rp, const float4* __restrict__ ap,
        const float4* __restrict__ cf, const float4* __restrict__ fg,
        const float4* __restrict__ bg, float* __restrict__ stats) {
    const int b = blockIdx.y;
    const int base = b * HW4 + blockIdx.x * (3 * 256) + threadIdx.x;

    float4 Art, Aat, Arp, Aap, Acf, Afg, Abg;
    float4 Brt, Bat, Brp, Bap, Bcf, Bfg, Bbg;
    float sfg = 0.f, sbg = 0.f, snum = 0.f, sden = 0.f;

#define LOADC(P, c) do { const int _i = base + (c) * 256;                     \
        P##rt = rt[_i]; P##at = at[_i]; P##rp = rp[_i]; P##ap = ap[_i];       \
        P##cf = cf[_i]; P##fg = fg[_i]; P##bg = bg[_i]; } while (0)
// Loads (mayLoad) cannot sink across an unknown-memory asm: pins issue point.
#define PIN() asm volatile("" ::: "memory")
#define ACCUM(P) do { _Pragma("unroll")                                       \
    for (int j = 0; j < 4; ++j) {                                             \
        float r = (&P##rt.x)[j] - (&P##rp.x)[j];                              \
        float a = (&P##at.x)[j] - (&P##ap.x)[j];                              \
        float c = (&P##cf.x)[j];                                              \
        float lt = (r * r + a * a) * c;                                       \
        float f = (&P##fg.x)[j], g = (&P##bg.x)[j];                           \
        float train = f + g;                                                  \
        sfg += f; sbg += g; snum += lt * train; sden += c * train;            \
    } } while (0)

    LOADC(A, 0); PIN();      // chunk 0 in flight
    LOADC(B, 1); PIN();      // chunk 1 in flight (14 loads outstanding)
    ACCUM(A);                // consume 0 while 1 flies
    LOADC(A, 2); PIN();      // chunk 2 in flight (reuses A regs)
    ACCUM(B);                // consume 1 while 2 flies
    ACCUM(A);                // consume 2

#undef LOADC
#undef PIN
#undef ACCUM

    wave_reduce4(sfg, sbg, snum, sden);
    __shared__ float sh[4][4];
    const int wave = threadIdx.x >> 6;
    if ((threadIdx.x & 63) == 0) {
        sh[wave][0] = sfg; sh[wave][1] = sbg; sh[wave][2] = snum; sh[wave][3] = sden;
    }
    __syncthreads();
    if (threadIdx.x < 4) {
        const int q = threadIdx.x;
        float s = sh[0][q] + sh[1][q] + sh[2][q] + sh[3][q];
        fadd_agent(&stats[q * 32 + b], s);   // q*32: S_FG/S_BG/S_NUMF/S_DENF
    }
}

// K2: one block per sample. Decide fast path (neg_num == bg_num -> hard == bg,
// proven exact) or run 4-pass radix-256 select for the exact k-th largest
// neg_loss value (uint bit pattern order == float order for non-negative).
__global__ __launch_bounds__(512) void k2_select(
        const float* __restrict__ rt, const float* __restrict__ at,
        const float* __restrict__ rp, const float* __restrict__ ap,
        const float* __restrict__ cf, const float* __restrict__ bg,
        float* __restrict__ stats) {
    const int b = blockIdx.x;
    const float fg_num = stats[S_FG + b];
    const float bg_num = stats[S_BG + b];
    int neg = (int)(fg_num * 3.0f);
    if (neg < 10000) neg = 10000;
    const int bgn = (int)bg_num;
    unsigned* flags = (unsigned*)stats;
    if (neg >= bgn) {
        // neg_num == bg_num: thresh is min bg loss (or 0) -> hard == bg exactly.
        if (threadIdx.x == 0) {
            flags[S_FLAG + b] = 1u;
            fadd_agent(&stats[S_GNUM], stats[S_NUMF + b]);
            fadd_agent(&stats[S_GDEN], stats[S_DENF + b]);
        }
        return;
    }
    if (threadIdx.x == 0) flags[S_FLAG + b] = 0u;

    __shared__ unsigned hist[256];
    __shared__ unsigned sh_prefix, sh_k;
    unsigned prefix = 0;
    unsigned k = (unsigned)neg;  // k >= 10000 >= 1 here
    const long base = (long)b * HW;
#pragma unroll 1
    for (int p = 3; p >= 0; --p) {
        for (int i = threadIdx.x; i < 256; i += blockDim.x) hist[i] = 0u;
        __syncthreads();
        const unsigned shift = 8u * (unsigned)p;
        const unsigned himask = (p == 3) ? 0u : (0xFFFFFFFFu << (shift + 8u));
#pragma unroll 1
        for (int i = threadIdx.x; i < HW; i += blockDim.x) {
            long g = base + i;
            float r = rt[g] - rp[g];
            float a = at[g] - ap[g];
            float lt = (r * r + a * a) * cf[g];
            float nl = lt * bg[g];
            unsigned v = __float_as_uint(nl);
            if ((v & himask) == prefix) atomicAdd(&hist[(v >> shift) & 255u], 1u);
        }
        __syncthreads();
        if (threadIdx.x == 0) {
            unsigned cum = 0;
            for (int bin = 255; bin >= 0; --bin) {
                unsigned c = hist[bin];
                if (cum + c >= k) {
                    sh_prefix = prefix | ((unsigned)bin << shift);
                    sh_k = k - cum;  // remaining rank within this bin
                    break;
                }
                cum += c;
            }
        }
        __syncthreads();
        prefix = sh_prefix;
        k = sh_k;
        __syncthreads();  // protect hist before next-pass zeroing
    }
    if (threadIdx.x == 0) stats[S_THR + b] = __uint_as_float(prefix);
}

// K3: masked sums for general-path samples only (early-exit on fast flag).
__global__ __launch_bounds__(256) void k3_general(
        const float4* __restrict__ rt, const float4* __restrict__ at,
        const float4* __restrict__ rp, const float4* __restrict__ ap,
        const float4* __restrict__ cf, const float4* __restrict__ fg,
        const float4* __restrict__ bg, float* __restrict__ stats) {
    const int b = blockIdx.y;
    if (((const unsigned*)stats)[S_FLAG + b] != 0u) return;
    const float thresh = stats[S_THR + b];
    const int base = b * HW4 + blockIdx.x * (256 * ITER) + threadIdx.x;
    float snum = 0.f, sden = 0.f, z0 = 0.f, z1 = 0.f;
#pragma unroll
    for (int it = 0; it < ITER; ++it) {
        const int idx = base + it * 256;
        float4 vrt = rt[idx], vat = at[idx], vrp = rp[idx], vap = ap[idx];
        float4 vcf = cf[idx], vfg = fg[idx], vbg = bg[idx];
#pragma unroll
        for (int j = 0; j < 4; ++j) {
            float r = (&vrt.x)[j] - (&vrp.x)[j];
            float a = (&vat.x)[j] - (&vap.x)[j];
            float c = (&vcf.x)[j];
            float lt = (r * r + a * a) * c;
            float f = (&vfg.x)[j], g = (&vbg.x)[j];
            float nl = lt * g;
            float hard = (g != 0.f && nl >= thresh) ? 1.f : 0.f;
            float train = hard + f;
            snum += lt * train;
            sden += c * train;
        }
    }
    wave_reduce4(snum, sden, z0, z1);
    __shared__ float sh[4][2];
    const int wave = threadIdx.x >> 6;
    if ((threadIdx.x & 63) == 0) { sh[wave][0] = snum; sh[wave][1] = sden; }
    __syncthreads();
    if (threadIdx.x < 2) {
        const int q = threadIdx.x;
        float s = sh[0][q] + sh[1][q] + sh[2][q] + sh[3][q];
        fadd_agent(&stats[S_GNUM + q], s);
    }
}

__global__ void k4_final(const float* __restrict__ stats, float* __restrict__ out) {
    out[0] = stats[S_GNUM] / (stats[S_GDEN] + 1e-7f);
}

extern "C" void kernel_launch(void* const* d_in, const int* in_sizes, int n_in,
                              void* d_out, int out_size, void* d_ws, size_t ws_size,
                              hipStream_t stream) {
    const float* rt = (const float*)d_in[0];
    const float* at = (const float*)d_in[1];
    const float* rp = (const float*)d_in[2];
    const float* ap = (const float*)d_in[3];
    const float* cf = (const float*)d_in[4];
    const float* fg = (const float*)d_in[5];
    const float* bg = (const float*)d_in[6];
    float* stats = (float*)d_ws;
    float* out = (float*)d_out;

    hipMemsetAsync(d_ws, 0, 1024, stream);

    dim3 grid1(K1_BLOCKS, BATCH);
    k1_stats<<<grid1, 256, 0, stream>>>((const float4*)rt, (const float4*)at,
                                        (const float4*)rp, (const float4*)ap,
                                        (const float4*)cf, (const float4*)fg,
                                        (const float4*)bg, stats);
    k2_select<<<BATCH, 512, 0, stream>>>(rt, at, rp, ap, cf, bg, stats);
    dim3 grid3(K3_BLOCKS, BATCH);
    k3_general<<<grid3, 256, 0, stream>>>((const float4*)rt, (const float4*)at,
                                          (const float4*)rp, (const float4*)ap,
                                          (const float4*)cf, (const float4*)fg,
                                          (const float4*)bg, stats);
    k4_final<<<1, 1, 0, stream>>>(stats, out);
}

// Round 7
// 164.446 us; speedup vs baseline: 1.0181x; 1.0174x over previous
//
#include <hip/hip_runtime.h>

#define HW (384 * 384)      // 147456 per sample
#define BATCH 32
#define HW4 (HW / 4)        // 36864 float4 per sample
#define ITER 2              // chunks per thread in k1/k3
#define BLOCKS_PER_SAMPLE 72    // 72 * 256 * 4 * ITER = 147456
// R7: inline-asm loads. R3-R6 showed the compiler NEVER keeps >1 chunk of
// loads in flight (VGPR 32-40), pinning device load issue at ~1.2 instr/cy.
// Here all 14 global_load_dwordx4 are volatile asm (compiler can't reorder
// or insert waits), consumed under explicit vmcnt(7)/vmcnt(0).

// stats layout in d_ws (4-byte slots):
//   [0..31] fg_num | [32..63] bg_num | [64..95] num_fast | [96..127] den_fast
//   [128..159] thresh | [160..191] flag | [192] gnum | [193] gden
#define S_FG 0
#define S_BG 32
#define S_NUMF 64
#define S_DENF 96
#define S_THR 128
#define S_FLAG 160
#define S_GNUM 192
#define S_GDEN 193

// Native device-scope fp32 atomic add (global_atomic_add_f32), avoiding the
// CAS retry loop hipcc emits for plain atomicAdd(float*) (R0->R1: 233->66us).
__device__ __forceinline__ void fadd_agent(float* p, float v) {
    __hip_atomic_fetch_add(p, v, __ATOMIC_RELAXED, __HIP_MEMORY_SCOPE_AGENT);
}

__device__ __forceinline__ void wave_reduce4(float& a, float& b, float& c, float& d) {
#pragma unroll
    for (int off = 32; off; off >>= 1) {
        a += __shfl_xor(a, off);
        b += __shfl_xor(b, off);
        c += __shfl_xor(c, off);
        d += __shfl_xor(d, off);
    }
}

// Raw in-flight load: compiler sees the def at issue point, inserts NO wait.
// Consumption MUST follow an explicit s_waitcnt (see WAITV below).
__device__ __forceinline__ float4 gld(const float4* p) {
    float4 r;
    asm volatile("global_load_dwordx4 %0, %1, off" : "=v"(r) : "v"(p) : "memory");
    return r;
}
// Counted wait + scheduling fence (rule #18: without sched_barrier(0) the
// compiler may hoist register-only consumers above the asm waitcnt).
#define WAITV(n) do { asm volatile("s_waitcnt vmcnt(" #n ")" ::: "memory"); \
                      __builtin_amdgcn_sched_barrier(0); } while (0)

// K1: one pass over all 7 arrays. Per-sample fg_num, bg_num, and speculative
// fast-path sums (train_mask = fg + bg).
__global__ __launch_bounds__(256) void k1_stats(
        const float4* __restrict__ rt, const float4* __restrict__ at,
        const float4* __restrict__ rp, const float4* __restrict__ ap,
        const float4* __restrict__ cf, const float4* __restrict__ fg,
        const float4* __restrict__ bg, float* __restrict__ stats) {
    const int b = blockIdx.y;
    const int i0 = b * HW4 + blockIdx.x * (256 * ITER) + threadIdx.x;
    const int i1 = i0 + 256;

    // Issue all 14 loads back-to-back: 14 outstanding VMEM ops per thread.
    float4 Art = gld(rt + i0), Aat = gld(at + i0), Arp = gld(rp + i0),
           Aap = gld(ap + i0), Acf = gld(cf + i0), Afg = gld(fg + i0),
           Abg = gld(bg + i0);
    float4 Brt = gld(rt + i1), Bat = gld(at + i1), Brp = gld(rp + i1),
           Bap = gld(ap + i1), Bcf = gld(cf + i1), Bfg = gld(fg + i1),
           Bbg = gld(bg + i1);

    float sfg = 0.f, sbg = 0.f, snum = 0.f, sden = 0.f;
#define ACCUM(P) do { _Pragma("unroll")                                       \
    for (int j = 0; j < 4; ++j) {                                             \
        float r = (&P##rt.x)[j] - (&P##rp.x)[j];                              \
        float a = (&P##at.x)[j] - (&P##ap.x)[j];                              \
        float c = (&P##cf.x)[j];                                              \
        float lt = (r * r + a * a) * c;                                       \
        float f = (&P##fg.x)[j], g = (&P##bg.x)[j];                           \
        float train = f + g;                                                  \
        sfg += f; sbg += g; snum += lt * train; sden += c * train;            \
    } } while (0)

    WAITV(7);    // chunk A landed; B's 7 still in flight
    ACCUM(A);
    WAITV(0);    // chunk B landed
    ACCUM(B);
#undef ACCUM

    wave_reduce4(sfg, sbg, snum, sden);
    __shared__ float sh[4][4];
    const int wave = threadIdx.x >> 6;
    if ((threadIdx.x & 63) == 0) {
        sh[wave][0] = sfg; sh[wave][1] = sbg; sh[wave][2] = snum; sh[wave][3] = sden;
    }
    __syncthreads();
    if (threadIdx.x < 4) {
        const int q = threadIdx.x;
        float s = sh[0][q] + sh[1][q] + sh[2][q] + sh[3][q];
        fadd_agent(&stats[q * 32 + b], s);   // q*32: S_FG/S_BG/S_NUMF/S_DENF
    }
}

// K2: one block per sample. Decide fast path (neg_num == bg_num -> hard == bg,
// proven exact) or run 4-pass radix-256 select for the exact k-th largest
// neg_loss value (uint bit pattern order == float order for non-negative).
__global__ __launch_bounds__(512) void k2_select(
        const float* __restrict__ rt, const float* __restrict__ at,
        const float* __restrict__ rp, const float* __restrict__ ap,
        const float* __restrict__ cf, const float* __restrict__ bg,
        float* __restrict__ stats) {
    const int b = blockIdx.x;
    const float fg_num = stats[S_FG + b];
    const float bg_num = stats[S_BG + b];
    int neg = (int)(fg_num * 3.0f);
    if (neg < 10000) neg = 10000;
    const int bgn = (int)bg_num;
    unsigned* flags = (unsigned*)stats;
    if (neg >= bgn) {
        // neg_num == bg_num: thresh is min bg loss (or 0) -> hard == bg exactly.
        if (threadIdx.x == 0) {
            flags[S_FLAG + b] = 1u;
            fadd_agent(&stats[S_GNUM], stats[S_NUMF + b]);
            fadd_agent(&stats[S_GDEN], stats[S_DENF + b]);
        }
        return;
    }
    if (threadIdx.x == 0) flags[S_FLAG + b] = 0u;

    __shared__ unsigned hist[256];
    __shared__ unsigned sh_prefix, sh_k;
    unsigned prefix = 0;
    unsigned k = (unsigned)neg;  // k >= 10000 >= 1 here
    const long base = (long)b * HW;
#pragma unroll 1
    for (int p = 3; p >= 0; --p) {
        for (int i = threadIdx.x; i < 256; i += blockDim.x) hist[i] = 0u;
        __syncthreads();
        const unsigned shift = 8u * (unsigned)p;
        const unsigned himask = (p == 3) ? 0u : (0xFFFFFFFFu << (shift + 8u));
#pragma unroll 1
        for (int i = threadIdx.x; i < HW; i += blockDim.x) {
            long g = base + i;
            float r = rt[g] - rp[g];
            float a = at[g] - ap[g];
            float lt = (r * r + a * a) * cf[g];
            float nl = lt * bg[g];
            unsigned v = __float_as_uint(nl);
            if ((v & himask) == prefix) atomicAdd(&hist[(v >> shift) & 255u], 1u);
        }
        __syncthreads();
        if (threadIdx.x == 0) {
            unsigned cum = 0;
            for (int bin = 255; bin >= 0; --bin) {
                unsigned c = hist[bin];
                if (cum + c >= k) {
                    sh_prefix = prefix | ((unsigned)bin << shift);
                    sh_k = k - cum;  // remaining rank within this bin
                    break;
                }
                cum += c;
            }
        }
        __syncthreads();
        prefix = sh_prefix;
        k = sh_k;
        __syncthreads();  // protect hist before next-pass zeroing
    }
    if (threadIdx.x == 0) stats[S_THR + b] = __uint_as_float(prefix);
}

// K3: masked sums for general-path samples only (early-exit on fast flag).
__global__ __launch_bounds__(256) void k3_general(
        const float4* __restrict__ rt, const float4* __restrict__ at,
        const float4* __restrict__ rp, const float4* __restrict__ ap,
        const float4* __restrict__ cf, const float4* __restrict__ fg,
        const float4* __restrict__ bg, float* __restrict__ stats) {
    const int b = blockIdx.y;
    if (((const unsigned*)stats)[S_FLAG + b] != 0u) return;
    const float thresh = stats[S_THR + b];
    const int base = b * HW4 + blockIdx.x * (256 * ITER) + threadIdx.x;
    float snum = 0.f, sden = 0.f, z0 = 0.f, z1 = 0.f;
#pragma unroll
    for (int it = 0; it < ITER; ++it) {
        const int idx = base + it * 256;
        float4 vrt = rt[idx], vat = at[idx], vrp = rp[idx], vap = ap[idx];
        float4 vcf = cf[idx], vfg = fg[idx], vbg = bg[idx];
#pragma unroll
        for (int j = 0; j < 4; ++j) {
            float r = (&vrt.x)[j] - (&vrp.x)[j];
            float a = (&vat.x)[j] - (&vap.x)[j];
            float c = (&vcf.x)[j];
            float lt = (r * r + a * a) * c;
            float f = (&vfg.x)[j], g = (&vbg.x)[j];
            float nl = lt * g;
            float hard = (g != 0.f && nl >= thresh) ? 1.f : 0.f;
            float train = hard + f;
            snum += lt * train;
            sden += c * train;
        }
    }
    wave_reduce4(snum, sden, z0, z1);
    __shared__ float sh[4][2];
    const int wave = threadIdx.x >> 6;
    if ((threadIdx.x & 63) == 0) { sh[wave][0] = snum; sh[wave][1] = sden; }
    __syncthreads();
    if (threadIdx.x < 2) {
        const int q = threadIdx.x;
        float s = sh[0][q] + sh[1][q] + sh[2][q] + sh[3][q];
        fadd_agent(&stats[S_GNUM + q], s);
    }
}

__global__ void k4_final(const float* __restrict__ stats, float* __restrict__ out) {
    out[0] = stats[S_GNUM] / (stats[S_GDEN] + 1e-7f);
}

extern "C" void kernel_launch(void* const* d_in, const int* in_sizes, int n_in,
                              void* d_out, int out_size, void* d_ws, size_t ws_size,
                              hipStream_t stream) {
    const float* rt = (const float*)d_in[0];
    const float* at = (const float*)d_in[1];
    const float* rp = (const float*)d_in[2];
    const float* ap = (const float*)d_in[3];
    const float* cf = (const float*)d_in[4];
    const float* fg = (const float*)d_in[5];
    const float* bg = (const float*)d_in[6];
    float* stats = (float*)d_ws;
    float* out = (float*)d_out;

    hipMemsetAsync(d_ws, 0, 1024, stream);

    dim3 grid(BLOCKS_PER_SAMPLE, BATCH);
    k1_stats<<<grid, 256, 0, stream>>>((const float4*)rt, (const float4*)at,
                                       (const float4*)rp, (const float4*)ap,
                                       (const float4*)cf, (const float4*)fg,
                                       (const float4*)bg, stats);
    k2_select<<<BATCH, 512, 0, stream>>>(rt, at, rp, ap, cf, bg, stats);
    k3_general<<<grid, 256, 0, stream>>>((const float4*)rt, (const float4*)at,
                                         (const float4*)rp, (const float4*)ap,
                                         (const float4*)cf, (const float4*)fg,
                                         (const float4*)bg, stats);
    k4_final<<<1, 1, 0, stream>>>(stats, out);
}